// Round 9
// baseline (76.399 us; speedup 1.0000x reference)
//
#include <hip/hip_runtime.h>

#define NB     4
#define NPTS   8192
#define NTP    (NPTS / 2)      // 4096 target-pairs per batch
#define TPB    256             // threads per block (4 waves)
#define QPC    16              // queries per chunk (SGPR-resident: 64 SGPRs)
#define ITERS  (NTP / TPB)     // 16 target-pair iterations per chunk

typedef float v4f __attribute__((ext_vector_type(4)));

// nq[i] = (x, y, z, 0.5||p||^2) per input1 point (queries).
// tp: per input2 target-pair p: tl=(x0,x1,y0,y1), th=(z0,z1,w0,w1).
__global__ void pack_pts(const float* __restrict__ in1, const float* __restrict__ in2,
                         v4f* __restrict__ nq, v4f* __restrict__ tp) {
    int i = blockIdx.x * blockDim.x + threadIdx.x;   // 49152 = 192*256 exact
    if (i < NB * NPTS) {
        float x = in1[3*i], y = in1[3*i+1], z = in1[3*i+2];
        nq[i] = (v4f){x, y, z, 0.5f * (x*x + y*y + z*z)};
    } else {
        int p = i - NB * NPTS;                       // [0, NB*NTP)
        float x0 = in2[6*p+0], y0 = in2[6*p+1], z0 = in2[6*p+2];
        float x1 = in2[6*p+3], y1 = in2[6*p+4], z1 = in2[6*p+5];
        tp[2*p]   = (v4f){x0, x1, y0, y1};
        tp[2*p+1] = (v4f){z0, z1, 0.5f*(x0*x0 + y0*y0 + z0*z0),
                                  0.5f*(x1*x1 + y1*y1 + z1*z1)};
    }
}

// f(q,t) = qw + tw - q.t = 0.5||q-t||^2, computed ONCE per pair.
// Queries are wave-uniform -> compiler keeps them in SGPRs; every FMA reads
// exactly one SGPR operand (free). Row (query) mins in registers; col (target)
// mins via v_min3 into per-iter c0/c1, clamped >=0 (monotonic uint key) and
// flushed with LDS ds_min (distinct per-lane addrs -> no contention).
// SLOTS blocks per batch, each owning NPTS/SLOTS queries x all targets.
template<int SLOTS>
__launch_bounds__(TPB, 4)   // VGPR cap 128; expect ~48 -> 4 blocks/CU (4 waves/SIMD)
__global__ void chamfer_min(const v4f* __restrict__ nq, const v4f* __restrict__ tp,
                            unsigned* __restrict__ colbuf, float* __restrict__ accum) {
    constexpr int NCHUNK = (NPTS / SLOTS) / QPC;
    __shared__ unsigned colkey[NPTS];   // [idx]: target 2*idx, [NTP+idx]: 2*idx+1
    __shared__ float red[4][QPC];

    const int slot = blockIdx.x;
    const int bb   = blockIdx.y;
    const int t    = threadIdx.x;
    const int lane = t & 63;
    const int wave = t >> 6;

    uint4 ff = make_uint4(~0u, ~0u, ~0u, ~0u);
#pragma unroll
    for (int k = 0; k < NPTS / 4 / TPB; ++k) ((uint4*)colkey)[t + k * TPB] = ff;
    __syncthreads();

    const v4f* __restrict__ Tb = tp + (size_t)bb * (2 * NTP);
    const v4f* __restrict__ Qb = nq + (size_t)bb * NPTS + slot * (NCHUNK * QPC);

#pragma unroll 1
    for (int chunk = 0; chunk < NCHUNK; ++chunk) {
        // 16 wave-uniform queries -> s_load into SGPRs (no VGPR cost, no movs)
        float qx[QPC], qy[QPC], qz[QPC], qw[QPC];
#pragma unroll
        for (int j = 0; j < QPC; ++j) {
            v4f q = Qb[chunk * QPC + j];
            qx[j] = q.x; qy[j] = q.y; qz[j] = q.z; qw[j] = q.w;
        }

        float accR[QPC];
#pragma unroll
        for (int j = 0; j < QPC; ++j) accR[j] = 1e30f;

        int idx = t;
        v4f tl = Tb[2 * idx], th = Tb[2 * idx + 1];

#pragma unroll 1
        for (int it = 0; it < ITERS; ++it) {
            int nidx = (idx + TPB) & (NTP - 1);          // wrap: hot re-read
            v4f ntl = Tb[2 * nidx], nth = Tb[2 * nidx + 1];

            float x0 = tl.x, x1 = tl.y, y0 = tl.z, y1 = tl.w;
            float z0 = th.x, z1 = th.y, w0 = th.z, w1 = th.w;
            float c0 = 1e30f, c1 = 1e30f;
#pragma unroll
            for (int j = 0; j < QPC; j += 2) {
                float f0 = fmaf(-qx[j],   x0, fmaf(-qy[j],   y0, fmaf(-qz[j],   z0, w0 + qw[j])));
                float f1 = fmaf(-qx[j],   x1, fmaf(-qy[j],   y1, fmaf(-qz[j],   z1, w1 + qw[j])));
                float g0 = fmaf(-qx[j+1], x0, fmaf(-qy[j+1], y0, fmaf(-qz[j+1], z0, w0 + qw[j+1])));
                float g1 = fmaf(-qx[j+1], x1, fmaf(-qy[j+1], y1, fmaf(-qz[j+1], z1, w1 + qw[j+1])));
                asm("v_min3_f32 %0, %0, %1, %2" : "+v"(accR[j])   : "v"(f0), "v"(f1));
                asm("v_min3_f32 %0, %0, %1, %2" : "+v"(accR[j+1]) : "v"(g0), "v"(g1));
                asm("v_min3_f32 %0, %0, %1, %2" : "+v"(c0)        : "v"(f0), "v"(g0));
                asm("v_min3_f32 %0, %0, %1, %2" : "+v"(c1)        : "v"(f1), "v"(g1));
            }
            atomicMin(&colkey[idx],       __float_as_uint(fmaxf(c0, 0.0f)));
            atomicMin(&colkey[NTP + idx], __float_as_uint(fmaxf(c1, 0.0f)));
            tl = ntl; th = nth; idx = nidx;
        }

        // row epilogue: wave min -> cross-wave min -> dist sum -> atomicAdd
#pragma unroll
        for (int j = 0; j < QPC; ++j) {
            float a = accR[j];
            a = fminf(a, __shfl_xor(a, 32));
            a = fminf(a, __shfl_xor(a, 16));
            a = fminf(a, __shfl_xor(a, 8));
            a = fminf(a, __shfl_xor(a, 4));
            a = fminf(a, __shfl_xor(a, 2));
            a = fminf(a, __shfl_xor(a, 1));
            accR[j] = a;
        }
        if (lane == 0) {
#pragma unroll
            for (int j = 0; j < QPC; j += 4)
                *(v4f*)&red[wave][j] = (v4f){accR[j], accR[j+1], accR[j+2], accR[j+3]};
        }
        __syncthreads();
        if (t < QPC) {
            float m = fminf(fminf(red[0][t], red[1][t]), fminf(red[2][t], red[3][t]));
            float dist = fmaxf(2.0f * m, 0.0f);
#pragma unroll
            for (int off = 8; off > 0; off >>= 1)
                dist += __shfl_xor(dist, off, 16);
            if (t == 0) atomicAdd(accum, dist);
        }
        __syncthreads();
    }

    // col partials -> global (plain coalesced stores; combine kernel reduces)
    uint4* cb = (uint4*)(colbuf + (size_t)(bb * SLOTS + slot) * NPTS);
#pragma unroll
    for (int k = 0; k < NPTS / 4 / TPB; ++k) cb[t + k * TPB] = ((uint4*)colkey)[t + k * TPB];
}

// Reduce SLOTS slot-partials per target, sum distances, atomicAdd.
template<int SLOTS>
__global__ void col_combine(const unsigned* __restrict__ colbuf, float* __restrict__ accum) {
    int tid = blockIdx.x * blockDim.x + threadIdx.x;   // 32768 threads
    int bb  = tid >> 13;
    int m   = tid & (NPTS - 1);
    const unsigned* cb = colbuf + (size_t)bb * SLOTS * NPTS + m;
    unsigned k = ~0u;
#pragma unroll 8
    for (int s = 0; s < SLOTS; ++s) k = min(k, cb[(size_t)s * NPTS]);
    float dist = 2.0f * __uint_as_float(k);            // already clamped >= 0
    for (int off = 32; off > 0; off >>= 1) dist += __shfl_xor(dist, off, 64);
    if ((threadIdx.x & 63) == 0) atomicAdd(accum, dist);
}

__global__ void finish(const float* __restrict__ accum, float* __restrict__ out) {
    out[0] = accum[0] * (1.0f / (NB * NPTS));
}

extern "C" void kernel_launch(void* const* d_in, const int* in_sizes, int n_in,
                              void* d_out, int out_size, void* d_ws, size_t ws_size,
                              hipStream_t stream) {
    const float* in1 = (const float*)d_in[0];
    const float* in2 = (const float*)d_in[1];

    char* ws = (char*)d_ws;
    float*    accum  = (float*)ws;                               // 1 float
    v4f*      nq     = (v4f*)(ws + 256);                         // 512 KB
    v4f*      tp     = nq + (size_t)NB * NPTS;                   // 512 KB
    unsigned* colbuf = (unsigned*)(tp + (size_t)NB * NTP * 2);

    hipMemsetAsync(accum, 0, sizeof(float), stream);
    pack_pts<<<dim3((NB * NPTS + NB * NTP) / 256), 256, 0, stream>>>(in1, in2, nq, tp);

    const size_t base    = 256 + (size_t)NB * NPTS * 16 * 2;
    const size_t need256 = base + (size_t)256 * NB * NPTS * 4;   // ~34.6 MB
    const size_t need128 = base + (size_t)128 * NB * NPTS * 4;   // ~17.8 MB

    if (ws_size >= need256) {
        chamfer_min<256><<<dim3(256, NB), TPB, 0, stream>>>(nq, tp, colbuf, accum);
        col_combine<256><<<dim3(128), 256, 0, stream>>>(colbuf, accum);
    } else if (ws_size >= need128) {
        chamfer_min<128><<<dim3(128, NB), TPB, 0, stream>>>(nq, tp, colbuf, accum);
        col_combine<128><<<dim3(128), 256, 0, stream>>>(colbuf, accum);
    } else {
        chamfer_min<64><<<dim3(64, NB), TPB, 0, stream>>>(nq, tp, colbuf, accum);
        col_combine<64><<<dim3(128), 256, 0, stream>>>(colbuf, accum);
    }

    finish<<<1, 1, 0, stream>>>(accum, (float*)d_out);
}